// Round 17
// baseline (92.624 us; speedup 1.0000x reference)
//
#include <hip/hip_runtime.h>
#include <math.h>

#define B_    64
#define QLEN  32
#define DLEN  2048
#define WORD  300
#define ENT   128
#define AD    256
#define NK    11
#define VOCAB 50000

typedef __bf16 bf16x8 __attribute__((ext_vector_type(8)));
typedef __bf16 bf16x4 __attribute__((ext_vector_type(4)));
typedef float  f32x4  __attribute__((ext_vector_type(4)));

// ---------------------------------------------------------------------------
// W-pack: Wtp (K=320 pad, 160 tiles) + Wep (K=128, 64 tiles), MFMA-B order.
// ---------------------------------------------------------------------------
__global__ __launch_bounds__(256) void knrm_wpack(
    const float* __restrict__ Wt, const float* __restrict__ We,
    const float* __restrict__ bt, const float* __restrict__ be,
    __bf16* __restrict__ Wtp, __bf16* __restrict__ Wep,
    float* __restrict__ bias)
{
    const int idx = blockIdx.x * 256 + threadIdx.x;   // 0..14335
    if (idx < AD) bias[idx] = bt[idx] + be[idx];
    const int tile = idx >> 6, l = idx & 63;
    bf16x8 h;
    if (tile < 160) {
        const int s = tile >> 4, nb = tile & 15;
        const int col = nb * 16 + (l & 15);
        const int k0  = s * 32 + (l >> 4) * 8;
        #pragma unroll
        for (int j = 0; j < 8; ++j) {
            const int k = k0 + j;
            h[j] = (__bf16)((k < WORD) ? Wt[(size_t)k * AD + col] : 0.f);
        }
        *(bf16x8*)((char*)Wtp + (size_t)idx * 16) = h;
    } else {
        const int t2 = tile - 160;
        const int s = t2 >> 4, nb = t2 & 15;
        const int col = nb * 16 + (l & 15);
        const int k0  = s * 32 + (l >> 4) * 8;
        #pragma unroll
        for (int j = 0; j < 8; ++j)
            h[j] = (__bf16)We[(size_t)(k0 + j) * AD + col];
        *(bf16x8*)((char*)Wep + (size_t)(idx - 10240) * 16) = h;
    }
}

// ---------------------------------------------------------------------------
// P-GEMM (64 rows/block). P[v] = emb[v] @ Wt, bf16, permuted rows (512B):
// offset(col) = (col>>6)*128 + (col&15)*8 + ((col>>4)&3)*2  -> coalesced store
// ---------------------------------------------------------------------------
__global__ __launch_bounds__(256) void knrm_pgemm(
    const float* __restrict__ emb,
    const __bf16* __restrict__ Wtp,
    char* __restrict__ P)
{
    __shared__ __align__(16) char sm[40960];   // A [64][320] bf16 swizzled
    const int tid = threadIdx.x;
    const int v0  = blockIdx.x * 64;

    #pragma unroll
    for (int u = 0; u < 20; ++u) {
        const int idx  = u * 256 + tid;        // 0..5119
        const int r    = idx / 80;
        const int slot = idx - r * 80;
        const int k    = slot * 4;
        f32x4 v = (f32x4){0.f, 0.f, 0.f, 0.f};
        if (k < WORD && v0 + r < VOCAB)
            v = *(const f32x4*)(emb + (size_t)(v0 + r) * WORD + k);
        bf16x4 hv;
        #pragma unroll
        for (int c = 0; c < 4; ++c) hv[c] = (__bf16)v[c];
        *(bf16x4*)(sm + ((r * 640 + slot * 8) ^ ((r & 7) << 4))) = hv;
    }
    __syncthreads();

    const int w  = tid >> 6;
    const int l  = tid & 63;
    const int lr = l & 15;
    const int lg = l >> 4;

    f32x4 acc[4][4];
    #pragma unroll
    for (int mf = 0; mf < 4; ++mf)
        #pragma unroll
        for (int nf = 0; nf < 4; ++nf)
            acc[mf][nf] = (f32x4){0.f, 0.f, 0.f, 0.f};

    #pragma unroll
    for (int t = 0; t < 10; ++t) {
        bf16x8 a[4];
        #pragma unroll
        for (int mf = 0; mf < 4; ++mf) {
            const int row = mf * 16 + lr;
            a[mf] = *(const bf16x8*)(sm +
                ((row * 640 + t * 64 + lg * 16) ^ ((row & 7) << 4)));
        }
        bf16x8 wv[4];
        #pragma unroll
        for (int nf = 0; nf < 4; ++nf) {
            const int tile = t * 16 + w * 4 + nf;
            wv[nf] = *(const bf16x8*)((const char*)Wtp + (size_t)tile * 1024 + l * 16);
        }
        #pragma unroll
        for (int mf = 0; mf < 4; ++mf)
            #pragma unroll
            for (int nf = 0; nf < 4; ++nf)
                acc[mf][nf] = __builtin_amdgcn_mfma_f32_16x16x32_bf16(
                    a[mf], wv[nf], acc[mf][nf], 0, 0, 0);
    }

    #pragma unroll
    for (int mf = 0; mf < 4; ++mf)
        #pragma unroll
        for (int reg = 0; reg < 4; ++reg) {
            const int v = v0 + mf * 16 + lg * 4 + reg;
            if (v < VOCAB) {
                bf16x4 h;
                #pragma unroll
                for (int nf = 0; nf < 4; ++nf) h[nf] = (__bf16)acc[mf][nf][reg];
                *(bf16x4*)(P + (size_t)v * 512 + w * 128 + lr * 8) = h;
            }
        }
}

// ---------------------------------------------------------------------------
// Query transform: 32 rows (1 batch)/block, grid 64. relu(P[tok]+qent@We+b),
// normalize, zero padded rows; write qhatF in B-FRAGMENT TILE order.
// ---------------------------------------------------------------------------
__global__ __launch_bounds__(256) void knrm_qtrans(
    const int* __restrict__ tok,
    const float* __restrict__ ent,
    const char* __restrict__ Pp,
    const __bf16* __restrict__ Wep,
    const float* __restrict__ bias,
    char* __restrict__ qhatF)
{
    __shared__ __align__(16) char sm[16384 + 256];   // T [32][256] bf16 swz
    float* ssq  = (float*)(sm + 16384);              // [32]
    int*   toks = (int*)(sm + 16384 + 128);          // [32]

    const int tid  = threadIdx.x;
    const int row0 = blockIdx.x * 32;
    if (tid < 32) { toks[tid] = tok[row0 + tid] + 1; ssq[tid] = 0.f; }
    __syncthreads();

    const int wN = tid >> 6;
    const int l  = tid & 63;
    const int lr = l & 15;
    const int lg = l >> 4;
    const float* __restrict__ ebase = ent + (size_t)row0 * ENT;

    f32x4 acc[2][4];
    #pragma unroll
    for (int mf = 0; mf < 2; ++mf)
        #pragma unroll
        for (int nf = 0; nf < 4; ++nf)
            acc[mf][nf] = (f32x4){0.f, 0.f, 0.f, 0.f};

    bf16x4 pv[2][4];
    #pragma unroll
    for (int mf = 0; mf < 2; ++mf)
        #pragma unroll
        for (int reg = 0; reg < 4; ++reg) {
            const int r = mf * 16 + lg * 4 + reg;
            pv[mf][reg] = *(const bf16x4*)(Pp +
                (size_t)toks[r] * 512 + wN * 128 + lr * 8);
        }

    #pragma unroll
    for (int t = 0; t < 4; ++t) {
        bf16x8 a[2];
        #pragma unroll
        for (int mf = 0; mf < 2; ++mf) {
            const float* rp = ebase + (size_t)(mf * 16 + lr) * ENT + t * 32 + lg * 8;
            const f32x4 u0 = *(const f32x4*)rp;
            const f32x4 u1 = *(const f32x4*)(rp + 4);
            #pragma unroll
            for (int c = 0; c < 4; ++c) {
                a[mf][c]     = (__bf16)u0[c];
                a[mf][c + 4] = (__bf16)u1[c];
            }
        }
        bf16x8 wv[4];
        #pragma unroll
        for (int nf = 0; nf < 4; ++nf) {
            const int tile = t * 16 + wN * 4 + nf;
            wv[nf] = *(const bf16x8*)((const char*)Wep + (size_t)tile * 1024 + l * 16);
        }
        #pragma unroll
        for (int mf = 0; mf < 2; ++mf)
            #pragma unroll
            for (int nf = 0; nf < 4; ++nf)
                acc[mf][nf] = __builtin_amdgcn_mfma_f32_16x16x32_bf16(
                    a[mf], wv[nf], acc[mf][nf], 0, 0, 0);
    }

    float bv[4];
    #pragma unroll
    for (int nf = 0; nf < 4; ++nf) bv[nf] = bias[wN * 64 + nf * 16 + lr];
    float sq[2][4];
    #pragma unroll
    for (int mf = 0; mf < 2; ++mf)
        #pragma unroll
        for (int reg = 0; reg < 4; ++reg) {
            float s = 0.f;
            #pragma unroll
            for (int nf = 0; nf < 4; ++nf) {
                const float v = fmaxf(acc[mf][nf][reg] + (float)pv[mf][reg][nf]
                                      + bv[nf], 0.f);
                acc[mf][nf][reg] = v;
                s = fmaf(v, v, s);
            }
            sq[mf][reg] = s;
        }
    #pragma unroll
    for (int m = 1; m <= 8; m <<= 1)
        #pragma unroll
        for (int mf = 0; mf < 2; ++mf)
            #pragma unroll
            for (int reg = 0; reg < 4; ++reg)
                sq[mf][reg] += __shfl_xor(sq[mf][reg], m, 64);
    if (lr == 0) {
        #pragma unroll
        for (int mf = 0; mf < 2; ++mf)
            #pragma unroll
            for (int reg = 0; reg < 4; ++reg)
                atomicAdd(&ssq[mf * 16 + lg * 4 + reg], sq[mf][reg]);
    }
    #pragma unroll
    for (int mf = 0; mf < 2; ++mf)
        #pragma unroll
        for (int nf = 0; nf < 4; ++nf)
            #pragma unroll
            for (int reg = 0; reg < 4; ++reg) {
                const int r    = mf * 16 + lg * 4 + reg;
                const int col  = wN * 64 + nf * 16 + lr;
                const int byte = (r * 512 + col * 2) ^ ((r & 7) << 4);
                *(__bf16*)(sm + byte) = (__bf16)acc[mf][nf][reg];
            }
    __syncthreads();

    // readout in fragment-tile order: 16 tiles x 64 lanes x 16B
    char* qb = qhatF + (size_t)blockIdx.x * 16384;
    #pragma unroll
    for (int it = 0; it < 4; ++it) {
        const int idx = it * 256 + tid;         // 0..1023
        const int tile = idx >> 6, l2 = idx & 63;
        const int s  = tile >> 1, qt = tile & 1;
        const int row = qt * 16 + (l2 & 15);
        const int k0  = s * 32 + (l2 >> 4) * 8;
        const int byte = (row * 512 + k0 * 2) ^ ((row & 7) << 4);
        bf16x8 hv = *(const bf16x8*)(sm + byte);
        const float rn = (toks[row] == 0) ? 0.f
                                          : 1.f / (sqrtf(ssq[row]) + 1e-9f);
        #pragma unroll
        for (int j = 0; j < 8; ++j) hv[j] = (__bf16)((float)hv[j] * rn);
        *(bf16x8*)(qb + tile * 1024 + l2 * 16) = hv;
    }
}

// ---------------------------------------------------------------------------
// Fused v15: v14 + issue-early hoisting: qv (qhatF) loads and P gather moved
// to kernel start (deps: none / direct dtok reads). setprio around MFMA.
// ---------------------------------------------------------------------------
__global__ __launch_bounds__(256, 4) void knrm_fused5(
    const int* __restrict__ dtok,
    const float* __restrict__ dent,
    const char* __restrict__ Pp,
    const __bf16* __restrict__ Wep,
    const float* __restrict__ bias,
    const char* __restrict__ qhatF,
    __bf16* __restrict__ simsO)   // [B, DLEN, QLEN] bf16
{
    __shared__ __align__(16) char sm[16384 + 128];
    float* ssq = (float*)(sm + 16384);           // [32]

    const int tid = threadIdx.x;
    const int b   = blockIdx.y;
    const int d0  = blockIdx.x * 32;
    const int drow0 = b * DLEN + d0;
    const int w  = tid >> 6;
    const int l  = tid & 63;
    const int lr = l & 15;
    const int lg = l >> 4;
    const int dtile = w & 1, qtile = w >> 1;

    // ---- hoisted: qv prefetch (depends on nothing in this kernel) ----
    const char* __restrict__ qb = qhatF + (size_t)b * 16384;
    bf16x8 qv[8];
    #pragma unroll
    for (int s = 0; s < 8; ++s)
        qv[s] = *(const bf16x8*)(qb + (s * 2 + qtile) * 1024 + l * 16);

    // ---- hoisted: toks direct + P gather (overlaps dent stage) ----
    int tk[2][4];
    #pragma unroll
    for (int mf = 0; mf < 2; ++mf)
        #pragma unroll
        for (int reg = 0; reg < 4; ++reg)
            tk[mf][reg] = dtok[drow0 + mf * 16 + lg * 4 + reg] + 1;
    bf16x4 pv[2][4];
    #pragma unroll
    for (int mf = 0; mf < 2; ++mf)
        #pragma unroll
        for (int reg = 0; reg < 4; ++reg)
            pv[mf][reg] = *(const bf16x4*)(Pp +
                (size_t)tk[mf][reg] * 512 + w * 128 + lr * 8);

    if (tid < 32) ssq[tid] = 0.f;

    // stage dent -> Ab bf16 [32][128] swz
    #pragma unroll
    for (int u = 0; u < 4; ++u) {
        const int slot = u * 256 + tid;
        const int r    = slot >> 5;
        const int c4   = (slot & 31) * 4;
        const f32x4 v = *(const f32x4*)(dent + (size_t)(drow0 + r) * ENT + c4);
        bf16x4 hv;
        #pragma unroll
        for (int c = 0; c < 4; ++c) hv[c] = (__bf16)v[c];
        *(bf16x4*)(sm + ((r * 256 + c4 * 2) ^ ((r & 7) << 4))) = hv;
    }
    __syncthreads();

    f32x4 acc[2][4];
    #pragma unroll
    for (int mf = 0; mf < 2; ++mf)
        #pragma unroll
        for (int nf = 0; nf < 4; ++nf)
            acc[mf][nf] = (f32x4){0.f, 0.f, 0.f, 0.f};

    __builtin_amdgcn_s_setprio(1);
    #pragma unroll
    for (int t = 0; t < 4; ++t) {
        bf16x8 a[2];
        #pragma unroll
        for (int mf = 0; mf < 2; ++mf) {
            const int row = mf * 16 + lr;
            a[mf] = *(const bf16x8*)(sm +
                ((row * 256 + t * 64 + lg * 16) ^ ((row & 7) << 4)));
        }
        bf16x8 wv[4];
        #pragma unroll
        for (int nf = 0; nf < 4; ++nf) {
            const int tile = t * 16 + w * 4 + nf;
            wv[nf] = *(const bf16x8*)((const char*)Wep + (size_t)tile * 1024 + l * 16);
        }
        #pragma unroll
        for (int mf = 0; mf < 2; ++mf)
            #pragma unroll
            for (int nf = 0; nf < 4; ++nf)
                acc[mf][nf] = __builtin_amdgcn_mfma_f32_16x16x32_bf16(
                    a[mf], wv[nf], acc[mf][nf], 0, 0, 0);
    }
    __builtin_amdgcn_s_setprio(0);
    __syncthreads();   // Ab reads done; region reusable as T

    float bv[4];
    #pragma unroll
    for (int nf = 0; nf < 4; ++nf) bv[nf] = bias[w * 64 + nf * 16 + lr];
    float sq[2][4];
    #pragma unroll
    for (int mf = 0; mf < 2; ++mf)
        #pragma unroll
        for (int reg = 0; reg < 4; ++reg) {
            float s = 0.f;
            #pragma unroll
            for (int nf = 0; nf < 4; ++nf) {
                const float v = fmaxf(acc[mf][nf][reg] + (float)pv[mf][reg][nf]
                                      + bv[nf], 0.f);
                acc[mf][nf][reg] = v;
                s = fmaf(v, v, s);
            }
            sq[mf][reg] = s;
        }
    #pragma unroll
    for (int m = 1; m <= 8; m <<= 1)
        #pragma unroll
        for (int mf = 0; mf < 2; ++mf)
            #pragma unroll
            for (int reg = 0; reg < 4; ++reg)
                sq[mf][reg] += __shfl_xor(sq[mf][reg], m, 64);
    if (lr == 0) {
        #pragma unroll
        for (int mf = 0; mf < 2; ++mf)
            #pragma unroll
            for (int reg = 0; reg < 4; ++reg)
                atomicAdd(&ssq[mf * 16 + lg * 4 + reg], sq[mf][reg]);
    }
    // T write [doc][256] bf16: byte = doc*512 + (col*2 ^ ((doc&15)<<4))
    #pragma unroll
    for (int mf = 0; mf < 2; ++mf)
        #pragma unroll
        for (int nf = 0; nf < 4; ++nf)
            #pragma unroll
            for (int reg = 0; reg < 4; ++reg) {
                const int doc  = mf * 16 + lg * 4 + reg;
                const int col  = w * 64 + nf * 16 + lr;
                const int byte = doc * 512 + ((col * 2) ^ ((doc & 15) << 4));
                *(__bf16*)(sm + byte) = (__bf16)acc[mf][nf][reg];
            }
    __syncthreads();   // T + ssq visible

    // sims: wave -> dtile (16 docs, M), qtile (16 q, N); qv prefetched
    const int tdoc = dtile * 16 + lr;
    f32x4 s0 = (f32x4){0.f, 0.f, 0.f, 0.f};
    __builtin_amdgcn_s_setprio(1);
    #pragma unroll
    for (int s = 0; s < 8; ++s) {
        const bf16x8 ta = *(const bf16x8*)(sm +
            (tdoc * 512 + ((s * 64 + lg * 16) ^ ((tdoc & 15) << 4))));
        s0 = __builtin_amdgcn_mfma_f32_16x16x32_bf16(ta, qv[s], s0, 0, 0, 0);
    }
    __builtin_amdgcn_s_setprio(0);

    // store normalized sims (bf16); mask via tk[dtile][reg]
    __bf16* so = simsO + ((size_t)b * DLEN + d0) * QLEN;
    #pragma unroll
    for (int reg = 0; reg < 4; ++reg) {
        const int doc = dtile * 16 + lg * 4 + reg;
        const float dnv = (tk[dtile][reg] == 0) ? 0.f
                                                : 1.f / (sqrtf(ssq[doc]) + 1e-9f);
        so[(size_t)doc * QLEN + qtile * 16 + lr] = (__bf16)(s0[reg] * dnv);
    }
}

// ---------------------------------------------------------------------------
// Streaming RBF pass: grid (16, 64), 256 thr. Each block: 128 docs x 32 q.
// bf16 sims input; sigma=0.001 kernel guarded (exact 0 below 0.985 in fp32).
// ---------------------------------------------------------------------------
__global__ __launch_bounds__(256) void knrm_rbf(
    const __bf16* __restrict__ simsI,
    float* __restrict__ ksum,
    float* __restrict__ simsum)
{
    __shared__ float red[384];
    const int tid = threadIdx.x;
    const int b   = blockIdx.y;
    const int d0  = blockIdx.x * 128;
    const int q   = tid & 31;
    for (int i = tid; i < 384; i += 256) red[i] = 0.f;
    __syncthreads();

    const __bf16* __restrict__ base = simsI + ((size_t)b * DLEN + d0) * QLEN;
    float kq[12];
    #pragma unroll
    for (int k = 0; k < 12; ++k) kq[k] = 0.f;

    #pragma unroll
    for (int u = 0; u < 16; ++u) {
        const float sv = (float)base[u * 256 + tid];
        kq[11] += sv;
        const float v5 = __expf(fmaf(10.f, sv, -50.f * sv * sv));
        const float gU = __expf(20.f * sv);
        const float gD = __expf(-20.f * sv);
        float t = v5;
        kq[5] += t * 0.60653066f;
        t *= gD; kq[4] += t * 0.60653066f;
        t *= gD; kq[3] += t * 0.011108997f;
        t *= gD; kq[2] += t * 3.7266532e-06f;
        t *= gD; kq[1] += t * 2.2895532e-11f;
        t *= gD; kq[0] += t * 2.5767571e-18f;
        t = v5;
        t *= gU; kq[6] += t * 0.011108997f;
        t *= gU; kq[7] += t * 3.7266532e-06f;
        t *= gU; kq[8] += t * 2.2895532e-11f;
        t *= gU; kq[9] += t * 2.5767571e-18f;
        if (sv > 0.98f) {
            const float t10 = sv - 1.0f;
            kq[10] += __expf(-500000.f * t10 * t10);
        }
    }

    // lanes l and l^32 share q: combine, then LDS reduce
    #pragma unroll
    for (int k = 0; k < 12; ++k)
        kq[k] += __shfl_xor(kq[k], 32, 64);
    if ((tid & 63) < 32) {
        #pragma unroll
        for (int k = 0; k < 12; ++k)
            atomicAdd(&red[k * 32 + q], kq[k]);
    }
    __syncthreads();

    for (int i = tid; i < 384; i += 256) {
        const int k = i >> 5, qq = i & 31;
        if (k < NK) atomicAdd(&ksum[((size_t)b * NK + k) * QLEN + qq], red[i]);
        else        atomicAdd(&simsum[b * QLEN + qq], red[i]);
    }
}

// ---------------------------------------------------------------------------
__global__ __launch_bounds__(384) void knrm_final(
    const float* __restrict__ ksum,
    const float* __restrict__ simsum,
    const float* __restrict__ Wc, const float* __restrict__ bc,
    float* __restrict__ out)
{
    __shared__ float redq[NK][QLEN];
    __shared__ float res[NK];
    const int b = blockIdx.x;
    const int t = threadIdx.x;
    if (t < NK * QLEN) {
        const int k = t >> 5;
        const int q = t & 31;
        const float ms = simsum[b * QLEN + q];
        redq[k][q] = (ms != 0.0f)
            ? logf(ksum[((size_t)b * NK + k) * QLEN + q] + 1e-6f)
            : 0.0f;
    }
    __syncthreads();
    if (t < NK) {
        float s = 0.f;
        for (int q = 0; q < QLEN; ++q) s += redq[t][q];
        res[t] = s;
    }
    __syncthreads();
    if (t == 0) {
        float s = bc[0];
        for (int k = 0; k < NK; ++k) s += res[k] * Wc[k];
        out[b] = s;
    }
}

// ---------------------------------------------------------------------------
extern "C" void kernel_launch(void* const* d_in, const int* in_sizes, int n_in,
                              void* d_out, int out_size, void* d_ws, size_t ws_size,
                              hipStream_t stream)
{
    (void)in_sizes; (void)n_in; (void)out_size; (void)ws_size;
    const int*   qtok = (const int*)d_in[0];
    const int*   dtok = (const int*)d_in[1];
    const float* qent = (const float*)d_in[2];
    const float* dent = (const float*)d_in[3];
    const float* emb  = (const float*)d_in[4];
    const float* Wt   = (const float*)d_in[5];
    const float* bt   = (const float*)d_in[6];
    const float* We   = (const float*)d_in[7];
    const float* be   = (const float*)d_in[8];
    const float* Wc   = (const float*)d_in[9];
    const float* bc   = (const float*)d_in[10];
    float* out = (float*)d_out;

    char* ws = (char*)d_ws;
    const size_t off_qhat = 0;                               // 1,048,576
    const size_t off_Wtp  = off_qhat + 1048576;              //   163,840
    const size_t off_Wep  = off_Wtp  + 163840;               //    65,536
    const size_t off_bias = off_Wep  + 65536;                //     1,024
    const size_t off_ksum = off_bias + 1024;                 //    90,112
    const size_t off_sim  = off_ksum + 90112;                //     8,192
    const size_t off_P    = off_sim  + 8192;                 // 25,600,000
    const size_t off_sims = off_P    + 25600000;             //  8,388,608

    char*   qhatF = ws + off_qhat;
    __bf16* Wtp   = (__bf16*)(ws + off_Wtp);
    __bf16* Wep   = (__bf16*)(ws + off_Wep);
    float*  bias  = (float*)(ws + off_bias);
    float*  ksum  = (float*)(ws + off_ksum);
    float*  simsum= (float*)(ws + off_sim);
    char*   P     = ws + off_P;
    __bf16* simsX = (__bf16*)(ws + off_sims);

    hipMemsetAsync(ksum, 0, (size_t)(90112 + 8192), stream);

    knrm_wpack<<<dim3(56), dim3(256), 0, stream>>>(Wt, We, bt, be, Wtp, Wep, bias);
    knrm_pgemm<<<dim3((VOCAB + 63) / 64), dim3(256), 0, stream>>>(emb, Wtp, P);
    knrm_qtrans<<<dim3(64), dim3(256), 0, stream>>>(
        qtok, qent, P, Wep, bias, qhatF);
    knrm_fused5<<<dim3(DLEN / 32, B_), dim3(256), 0, stream>>>(
        dtok, dent, P, Wep, bias, qhatF, simsX);
    knrm_rbf<<<dim3(16, B_), dim3(256), 0, stream>>>(simsX, ksum, simsum);
    knrm_final<<<dim3(B_), dim3(384), 0, stream>>>(ksum, simsum, Wc, bc, out);
}

// Round 18
// 84.662 us; speedup vs baseline: 1.0940x; 1.0940x over previous
//
#include <hip/hip_runtime.h>
#include <math.h>

#define B_    64
#define QLEN  32
#define DLEN  2048
#define WORD  300
#define ENT   128
#define AD    256
#define NK    11
#define VOCAB 50000

typedef __bf16 bf16x8 __attribute__((ext_vector_type(8)));
typedef __bf16 bf16x4 __attribute__((ext_vector_type(4)));
typedef float  f32x4  __attribute__((ext_vector_type(4)));

// ---------------------------------------------------------------------------
// W-pack: Wtp (K=320 pad, 160 tiles) + Wep (K=128, 64 tiles), MFMA-B order.
// ---------------------------------------------------------------------------
__global__ __launch_bounds__(256) void knrm_wpack(
    const float* __restrict__ Wt, const float* __restrict__ We,
    const float* __restrict__ bt, const float* __restrict__ be,
    __bf16* __restrict__ Wtp, __bf16* __restrict__ Wep,
    float* __restrict__ bias)
{
    const int idx = blockIdx.x * 256 + threadIdx.x;   // 0..14335
    if (idx < AD) bias[idx] = bt[idx] + be[idx];
    const int tile = idx >> 6, l = idx & 63;
    bf16x8 h;
    if (tile < 160) {
        const int s = tile >> 4, nb = tile & 15;
        const int col = nb * 16 + (l & 15);
        const int k0  = s * 32 + (l >> 4) * 8;
        #pragma unroll
        for (int j = 0; j < 8; ++j) {
            const int k = k0 + j;
            h[j] = (__bf16)((k < WORD) ? Wt[(size_t)k * AD + col] : 0.f);
        }
        *(bf16x8*)((char*)Wtp + (size_t)idx * 16) = h;
    } else {
        const int t2 = tile - 160;
        const int s = t2 >> 4, nb = t2 & 15;
        const int col = nb * 16 + (l & 15);
        const int k0  = s * 32 + (l >> 4) * 8;
        #pragma unroll
        for (int j = 0; j < 8; ++j)
            h[j] = (__bf16)We[(size_t)(k0 + j) * AD + col];
        *(bf16x8*)((char*)Wep + (size_t)(idx - 10240) * 16) = h;
    }
}

// ---------------------------------------------------------------------------
// P-GEMM (64 rows/block). P[v] = emb[v] @ Wt, bf16, permuted rows (512B):
// offset(col) = (col>>6)*128 + (col&15)*8 + ((col>>4)&3)*2  -> coalesced store
// ---------------------------------------------------------------------------
__global__ __launch_bounds__(256) void knrm_pgemm(
    const float* __restrict__ emb,
    const __bf16* __restrict__ Wtp,
    char* __restrict__ P)
{
    __shared__ __align__(16) char sm[40960];   // A [64][320] bf16 swizzled
    const int tid = threadIdx.x;
    const int v0  = blockIdx.x * 64;

    #pragma unroll
    for (int u = 0; u < 20; ++u) {
        const int idx  = u * 256 + tid;        // 0..5119
        const int r    = idx / 80;
        const int slot = idx - r * 80;
        const int k    = slot * 4;
        f32x4 v = (f32x4){0.f, 0.f, 0.f, 0.f};
        if (k < WORD && v0 + r < VOCAB)
            v = *(const f32x4*)(emb + (size_t)(v0 + r) * WORD + k);
        bf16x4 hv;
        #pragma unroll
        for (int c = 0; c < 4; ++c) hv[c] = (__bf16)v[c];
        *(bf16x4*)(sm + ((r * 640 + slot * 8) ^ ((r & 7) << 4))) = hv;
    }
    __syncthreads();

    const int w  = tid >> 6;
    const int l  = tid & 63;
    const int lr = l & 15;
    const int lg = l >> 4;

    f32x4 acc[4][4];
    #pragma unroll
    for (int mf = 0; mf < 4; ++mf)
        #pragma unroll
        for (int nf = 0; nf < 4; ++nf)
            acc[mf][nf] = (f32x4){0.f, 0.f, 0.f, 0.f};

    #pragma unroll
    for (int t = 0; t < 10; ++t) {
        bf16x8 a[4];
        #pragma unroll
        for (int mf = 0; mf < 4; ++mf) {
            const int row = mf * 16 + lr;
            a[mf] = *(const bf16x8*)(sm +
                ((row * 640 + t * 64 + lg * 16) ^ ((row & 7) << 4)));
        }
        bf16x8 wv[4];
        #pragma unroll
        for (int nf = 0; nf < 4; ++nf) {
            const int tile = t * 16 + w * 4 + nf;
            wv[nf] = *(const bf16x8*)((const char*)Wtp + (size_t)tile * 1024 + l * 16);
        }
        #pragma unroll
        for (int mf = 0; mf < 4; ++mf)
            #pragma unroll
            for (int nf = 0; nf < 4; ++nf)
                acc[mf][nf] = __builtin_amdgcn_mfma_f32_16x16x32_bf16(
                    a[mf], wv[nf], acc[mf][nf], 0, 0, 0);
    }

    #pragma unroll
    for (int mf = 0; mf < 4; ++mf)
        #pragma unroll
        for (int reg = 0; reg < 4; ++reg) {
            const int v = v0 + mf * 16 + lg * 4 + reg;
            if (v < VOCAB) {
                bf16x4 h;
                #pragma unroll
                for (int nf = 0; nf < 4; ++nf) h[nf] = (__bf16)acc[mf][nf][reg];
                *(bf16x4*)(P + (size_t)v * 512 + w * 128 + lr * 8) = h;
            }
        }
}

// ---------------------------------------------------------------------------
// Query transform: 32 rows (1 batch)/block, grid 64. relu(P[tok]+qent@We+b),
// normalize, zero padded rows; write qhatF in B-FRAGMENT TILE order.
// ---------------------------------------------------------------------------
__global__ __launch_bounds__(256) void knrm_qtrans(
    const int* __restrict__ tok,
    const float* __restrict__ ent,
    const char* __restrict__ Pp,
    const __bf16* __restrict__ Wep,
    const float* __restrict__ bias,
    char* __restrict__ qhatF)
{
    __shared__ __align__(16) char sm[16384 + 256];   // T [32][256] bf16 swz
    float* ssq  = (float*)(sm + 16384);              // [32]
    int*   toks = (int*)(sm + 16384 + 128);          // [32]

    const int tid  = threadIdx.x;
    const int row0 = blockIdx.x * 32;
    if (tid < 32) { toks[tid] = tok[row0 + tid] + 1; ssq[tid] = 0.f; }
    __syncthreads();

    const int wN = tid >> 6;
    const int l  = tid & 63;
    const int lr = l & 15;
    const int lg = l >> 4;
    const float* __restrict__ ebase = ent + (size_t)row0 * ENT;

    f32x4 acc[2][4];
    #pragma unroll
    for (int mf = 0; mf < 2; ++mf)
        #pragma unroll
        for (int nf = 0; nf < 4; ++nf)
            acc[mf][nf] = (f32x4){0.f, 0.f, 0.f, 0.f};

    bf16x4 pv[2][4];
    #pragma unroll
    for (int mf = 0; mf < 2; ++mf)
        #pragma unroll
        for (int reg = 0; reg < 4; ++reg) {
            const int r = mf * 16 + lg * 4 + reg;
            pv[mf][reg] = *(const bf16x4*)(Pp +
                (size_t)toks[r] * 512 + wN * 128 + lr * 8);
        }

    #pragma unroll
    for (int t = 0; t < 4; ++t) {
        bf16x8 a[2];
        #pragma unroll
        for (int mf = 0; mf < 2; ++mf) {
            const float* rp = ebase + (size_t)(mf * 16 + lr) * ENT + t * 32 + lg * 8;
            const f32x4 u0 = *(const f32x4*)rp;
            const f32x4 u1 = *(const f32x4*)(rp + 4);
            #pragma unroll
            for (int c = 0; c < 4; ++c) {
                a[mf][c]     = (__bf16)u0[c];
                a[mf][c + 4] = (__bf16)u1[c];
            }
        }
        bf16x8 wv[4];
        #pragma unroll
        for (int nf = 0; nf < 4; ++nf) {
            const int tile = t * 16 + wN * 4 + nf;
            wv[nf] = *(const bf16x8*)((const char*)Wep + (size_t)tile * 1024 + l * 16);
        }
        #pragma unroll
        for (int mf = 0; mf < 2; ++mf)
            #pragma unroll
            for (int nf = 0; nf < 4; ++nf)
                acc[mf][nf] = __builtin_amdgcn_mfma_f32_16x16x32_bf16(
                    a[mf], wv[nf], acc[mf][nf], 0, 0, 0);
    }

    float bv[4];
    #pragma unroll
    for (int nf = 0; nf < 4; ++nf) bv[nf] = bias[wN * 64 + nf * 16 + lr];
    float sq[2][4];
    #pragma unroll
    for (int mf = 0; mf < 2; ++mf)
        #pragma unroll
        for (int reg = 0; reg < 4; ++reg) {
            float s = 0.f;
            #pragma unroll
            for (int nf = 0; nf < 4; ++nf) {
                const float v = fmaxf(acc[mf][nf][reg] + (float)pv[mf][reg][nf]
                                      + bv[nf], 0.f);
                acc[mf][nf][reg] = v;
                s = fmaf(v, v, s);
            }
            sq[mf][reg] = s;
        }
    #pragma unroll
    for (int m = 1; m <= 8; m <<= 1)
        #pragma unroll
        for (int mf = 0; mf < 2; ++mf)
            #pragma unroll
            for (int reg = 0; reg < 4; ++reg)
                sq[mf][reg] += __shfl_xor(sq[mf][reg], m, 64);
    if (lr == 0) {
        #pragma unroll
        for (int mf = 0; mf < 2; ++mf)
            #pragma unroll
            for (int reg = 0; reg < 4; ++reg)
                atomicAdd(&ssq[mf * 16 + lg * 4 + reg], sq[mf][reg]);
    }
    #pragma unroll
    for (int mf = 0; mf < 2; ++mf)
        #pragma unroll
        for (int nf = 0; nf < 4; ++nf)
            #pragma unroll
            for (int reg = 0; reg < 4; ++reg) {
                const int r    = mf * 16 + lg * 4 + reg;
                const int col  = wN * 64 + nf * 16 + lr;
                const int byte = (r * 512 + col * 2) ^ ((r & 7) << 4);
                *(__bf16*)(sm + byte) = (__bf16)acc[mf][nf][reg];
            }
    __syncthreads();

    // readout in fragment-tile order: 16 tiles x 64 lanes x 16B
    char* qb = qhatF + (size_t)blockIdx.x * 16384;
    #pragma unroll
    for (int it = 0; it < 4; ++it) {
        const int idx = it * 256 + tid;         // 0..1023
        const int tile = idx >> 6, l2 = idx & 63;
        const int s  = tile >> 1, qt = tile & 1;
        const int row = qt * 16 + (l2 & 15);
        const int k0  = s * 32 + (l2 >> 4) * 8;
        const int byte = (row * 512 + k0 * 2) ^ ((row & 7) << 4);
        bf16x8 hv = *(const bf16x8*)(sm + byte);
        const float rn = (toks[row] == 0) ? 0.f
                                          : 1.f / (sqrtf(ssq[row]) + 1e-9f);
        #pragma unroll
        for (int j = 0; j < 8; ++j) hv[j] = (__bf16)((float)hv[j] * rn);
        *(bf16x8*)(qb + tile * 1024 + l2 * 16) = hv;
    }
}

// ---------------------------------------------------------------------------
// Fused v14 (best measured): 32 docs/block, 4 waves, __launch_bounds__(256,4);
// tail stores normalized sims bf16. (R17's hoisting variant spilled: reverted.)
// ---------------------------------------------------------------------------
__global__ __launch_bounds__(256, 4) void knrm_fused5(
    const int* __restrict__ dtok,
    const float* __restrict__ dent,
    const char* __restrict__ Pp,
    const __bf16* __restrict__ Wep,
    const float* __restrict__ bias,
    const char* __restrict__ qhatF,
    __bf16* __restrict__ simsO)   // [B, DLEN, QLEN] bf16
{
    __shared__ __align__(16) char sm[16384 + 256];
    float* ssq  = (float*)(sm + 16384);          // [32]
    int*   toks = (int*)(sm + 16384 + 128);      // [32]

    const int tid = threadIdx.x;
    const int b   = blockIdx.y;
    const int d0  = blockIdx.x * 32;
    const int drow0 = b * DLEN + d0;
    const int w  = tid >> 6;
    const int l  = tid & 63;
    const int lr = l & 15;
    const int lg = l >> 4;

    if (tid < 32) { toks[tid] = dtok[drow0 + tid] + 1; ssq[tid] = 0.f; }

    // stage dent -> Ab bf16 [32][128] swz
    #pragma unroll
    for (int u = 0; u < 4; ++u) {
        const int slot = u * 256 + tid;
        const int r    = slot >> 5;
        const int c4   = (slot & 31) * 4;
        const f32x4 v = *(const f32x4*)(dent + (size_t)(drow0 + r) * ENT + c4);
        bf16x4 hv;
        #pragma unroll
        for (int c = 0; c < 4; ++c) hv[c] = (__bf16)v[c];
        *(bf16x4*)(sm + ((r * 256 + c4 * 2) ^ ((r & 7) << 4))) = hv;
    }
    __syncthreads();

    // early P gather
    bf16x4 pv[2][4];
    #pragma unroll
    for (int mf = 0; mf < 2; ++mf)
        #pragma unroll
        for (int reg = 0; reg < 4; ++reg) {
            const int doc = mf * 16 + lg * 4 + reg;
            pv[mf][reg] = *(const bf16x4*)(Pp +
                (size_t)toks[doc] * 512 + w * 128 + lr * 8);
        }

    f32x4 acc[2][4];
    #pragma unroll
    for (int mf = 0; mf < 2; ++mf)
        #pragma unroll
        for (int nf = 0; nf < 4; ++nf)
            acc[mf][nf] = (f32x4){0.f, 0.f, 0.f, 0.f};

    #pragma unroll
    for (int t = 0; t < 4; ++t) {
        bf16x8 a[2];
        #pragma unroll
        for (int mf = 0; mf < 2; ++mf) {
            const int row = mf * 16 + lr;
            a[mf] = *(const bf16x8*)(sm +
                ((row * 256 + t * 64 + lg * 16) ^ ((row & 7) << 4)));
        }
        bf16x8 wv[4];
        #pragma unroll
        for (int nf = 0; nf < 4; ++nf) {
            const int tile = t * 16 + w * 4 + nf;
            wv[nf] = *(const bf16x8*)((const char*)Wep + (size_t)tile * 1024 + l * 16);
        }
        #pragma unroll
        for (int mf = 0; mf < 2; ++mf)
            #pragma unroll
            for (int nf = 0; nf < 4; ++nf)
                acc[mf][nf] = __builtin_amdgcn_mfma_f32_16x16x32_bf16(
                    a[mf], wv[nf], acc[mf][nf], 0, 0, 0);
    }
    __syncthreads();   // Ab reads done; region reusable as T

    float bv[4];
    #pragma unroll
    for (int nf = 0; nf < 4; ++nf) bv[nf] = bias[w * 64 + nf * 16 + lr];
    float sq[2][4];
    #pragma unroll
    for (int mf = 0; mf < 2; ++mf)
        #pragma unroll
        for (int reg = 0; reg < 4; ++reg) {
            float s = 0.f;
            #pragma unroll
            for (int nf = 0; nf < 4; ++nf) {
                const float v = fmaxf(acc[mf][nf][reg] + (float)pv[mf][reg][nf]
                                      + bv[nf], 0.f);
                acc[mf][nf][reg] = v;
                s = fmaf(v, v, s);
            }
            sq[mf][reg] = s;
        }
    #pragma unroll
    for (int m = 1; m <= 8; m <<= 1)
        #pragma unroll
        for (int mf = 0; mf < 2; ++mf)
            #pragma unroll
            for (int reg = 0; reg < 4; ++reg)
                sq[mf][reg] += __shfl_xor(sq[mf][reg], m, 64);
    if (lr == 0) {
        #pragma unroll
        for (int mf = 0; mf < 2; ++mf)
            #pragma unroll
            for (int reg = 0; reg < 4; ++reg)
                atomicAdd(&ssq[mf * 16 + lg * 4 + reg], sq[mf][reg]);
    }
    // T write [doc][256] bf16: byte = doc*512 + (col*2 ^ ((doc&15)<<4))
    #pragma unroll
    for (int mf = 0; mf < 2; ++mf)
        #pragma unroll
        for (int nf = 0; nf < 4; ++nf)
            #pragma unroll
            for (int reg = 0; reg < 4; ++reg) {
                const int doc  = mf * 16 + lg * 4 + reg;
                const int col  = w * 64 + nf * 16 + lr;
                const int byte = doc * 512 + ((col * 2) ^ ((doc & 15) << 4));
                *(__bf16*)(sm + byte) = (__bf16)acc[mf][nf][reg];
            }
    __syncthreads();   // T + ssq visible

    // sims: wave -> dtile=w&1 (16 docs, M), qtile=w>>1 (16 q, N)
    const int dtile = w & 1, qtile = w >> 1;
    const int tdoc  = dtile * 16 + lr;
    const char* __restrict__ qb = qhatF + (size_t)b * 16384;
    f32x4 s0 = (f32x4){0.f, 0.f, 0.f, 0.f};
    #pragma unroll
    for (int s = 0; s < 8; ++s) {
        const bf16x8 ta = *(const bf16x8*)(sm +
            (tdoc * 512 + ((s * 64 + lg * 16) ^ ((tdoc & 15) << 4))));
        const bf16x8 qv = *(const bf16x8*)(qb + (s * 2 + qtile) * 1024 + l * 16);
        s0 = __builtin_amdgcn_mfma_f32_16x16x32_bf16(ta, qv, s0, 0, 0, 0);
    }

    // store normalized sims (bf16)
    __bf16* so = simsO + ((size_t)b * DLEN + d0) * QLEN;
    #pragma unroll
    for (int reg = 0; reg < 4; ++reg) {
        const int doc = dtile * 16 + lg * 4 + reg;
        const float dnv = (toks[doc] == 0) ? 0.f
                                           : 1.f / (sqrtf(ssq[doc]) + 1e-9f);
        so[(size_t)doc * QLEN + qtile * 16 + lr] = (__bf16)(s0[reg] * dnv);
    }
}

// ---------------------------------------------------------------------------
// Streaming RBF pass: grid (16, 64), 256 thr. Each block: 128 docs x 32 q.
// bf16 sims input; sigma=0.001 kernel guarded (exact 0 below 0.985 in fp32).
// ---------------------------------------------------------------------------
__global__ __launch_bounds__(256) void knrm_rbf(
    const __bf16* __restrict__ simsI,
    float* __restrict__ ksum,
    float* __restrict__ simsum)
{
    __shared__ float red[384];
    const int tid = threadIdx.x;
    const int b   = blockIdx.y;
    const int d0  = blockIdx.x * 128;
    const int q   = tid & 31;
    for (int i = tid; i < 384; i += 256) red[i] = 0.f;
    __syncthreads();

    const __bf16* __restrict__ base = simsI + ((size_t)b * DLEN + d0) * QLEN;
    float kq[12];
    #pragma unroll
    for (int k = 0; k < 12; ++k) kq[k] = 0.f;

    #pragma unroll
    for (int u = 0; u < 16; ++u) {
        const float sv = (float)base[u * 256 + tid];
        kq[11] += sv;
        const float v5 = __expf(fmaf(10.f, sv, -50.f * sv * sv));
        const float gU = __expf(20.f * sv);
        const float gD = __expf(-20.f * sv);
        float t = v5;
        kq[5] += t * 0.60653066f;
        t *= gD; kq[4] += t * 0.60653066f;
        t *= gD; kq[3] += t * 0.011108997f;
        t *= gD; kq[2] += t * 3.7266532e-06f;
        t *= gD; kq[1] += t * 2.2895532e-11f;
        t *= gD; kq[0] += t * 2.5767571e-18f;
        t = v5;
        t *= gU; kq[6] += t * 0.011108997f;
        t *= gU; kq[7] += t * 3.7266532e-06f;
        t *= gU; kq[8] += t * 2.2895532e-11f;
        t *= gU; kq[9] += t * 2.5767571e-18f;
        if (sv > 0.98f) {
            const float t10 = sv - 1.0f;
            kq[10] += __expf(-500000.f * t10 * t10);
        }
    }

    // lanes l and l^32 share q: combine, then LDS reduce
    #pragma unroll
    for (int k = 0; k < 12; ++k)
        kq[k] += __shfl_xor(kq[k], 32, 64);
    if ((tid & 63) < 32) {
        #pragma unroll
        for (int k = 0; k < 12; ++k)
            atomicAdd(&red[k * 32 + q], kq[k]);
    }
    __syncthreads();

    for (int i = tid; i < 384; i += 256) {
        const int k = i >> 5, qq = i & 31;
        if (k < NK) atomicAdd(&ksum[((size_t)b * NK + k) * QLEN + qq], red[i]);
        else        atomicAdd(&simsum[b * QLEN + qq], red[i]);
    }
}

// ---------------------------------------------------------------------------
__global__ __launch_bounds__(384) void knrm_final(
    const float* __restrict__ ksum,
    const float* __restrict__ simsum,
    const float* __restrict__ Wc, const float* __restrict__ bc,
    float* __restrict__ out)
{
    __shared__ float redq[NK][QLEN];
    __shared__ float res[NK];
    const int b = blockIdx.x;
    const int t = threadIdx.x;
    if (t < NK * QLEN) {
        const int k = t >> 5;
        const int q = t & 31;
        const float ms = simsum[b * QLEN + q];
        redq[k][q] = (ms != 0.0f)
            ? logf(ksum[((size_t)b * NK + k) * QLEN + q] + 1e-6f)
            : 0.0f;
    }
    __syncthreads();
    if (t < NK) {
        float s = 0.f;
        for (int q = 0; q < QLEN; ++q) s += redq[t][q];
        res[t] = s;
    }
    __syncthreads();
    if (t == 0) {
        float s = bc[0];
        for (int k = 0; k < NK; ++k) s += res[k] * Wc[k];
        out[b] = s;
    }
}

// ---------------------------------------------------------------------------
extern "C" void kernel_launch(void* const* d_in, const int* in_sizes, int n_in,
                              void* d_out, int out_size, void* d_ws, size_t ws_size,
                              hipStream_t stream)
{
    (void)in_sizes; (void)n_in; (void)out_size; (void)ws_size;
    const int*   qtok = (const int*)d_in[0];
    const int*   dtok = (const int*)d_in[1];
    const float* qent = (const float*)d_in[2];
    const float* dent = (const float*)d_in[3];
    const float* emb  = (const float*)d_in[4];
    const float* Wt   = (const float*)d_in[5];
    const float* bt   = (const float*)d_in[6];
    const float* We   = (const float*)d_in[7];
    const float* be   = (const float*)d_in[8];
    const float* Wc   = (const float*)d_in[9];
    const float* bc   = (const float*)d_in[10];
    float* out = (float*)d_out;

    char* ws = (char*)d_ws;
    const size_t off_qhat = 0;                               // 1,048,576
    const size_t off_Wtp  = off_qhat + 1048576;              //   163,840
    const size_t off_Wep  = off_Wtp  + 163840;               //    65,536
    const size_t off_bias = off_Wep  + 65536;                //     1,024
    const size_t off_ksum = off_bias + 1024;                 //    90,112
    const size_t off_sim  = off_ksum + 90112;                //     8,192
    const size_t off_P    = off_sim  + 8192;                 // 25,600,000
    const size_t off_sims = off_P    + 25600000;             //  8,388,608

    char*   qhatF = ws + off_qhat;
    __bf16* Wtp   = (__bf16*)(ws + off_Wtp);
    __bf16* Wep   = (__bf16*)(ws + off_Wep);
    float*  bias  = (float*)(ws + off_bias);
    float*  ksum  = (float*)(ws + off_ksum);
    float*  simsum= (float*)(ws + off_sim);
    char*   P     = ws + off_P;
    __bf16* simsX = (__bf16*)(ws + off_sims);

    hipMemsetAsync(ksum, 0, (size_t)(90112 + 8192), stream);

    knrm_wpack<<<dim3(56), dim3(256), 0, stream>>>(Wt, We, bt, be, Wtp, Wep, bias);
    knrm_pgemm<<<dim3((VOCAB + 63) / 64), dim3(256), 0, stream>>>(emb, Wtp, P);
    knrm_qtrans<<<dim3(64), dim3(256), 0, stream>>>(
        qtok, qent, P, Wep, bias, qhatF);
    knrm_fused5<<<dim3(DLEN / 32, B_), dim3(256), 0, stream>>>(
        dtok, dent, P, Wep, bias, qhatF, simsX);
    knrm_rbf<<<dim3(16, B_), dim3(256), 0, stream>>>(simsX, ksum, simsum);
    knrm_final<<<dim3(B_), dim3(384), 0, stream>>>(ksum, simsum, Wc, bc, out);
}

// Round 19
// 84.163 us; speedup vs baseline: 1.1005x; 1.0059x over previous
//
#include <hip/hip_runtime.h>
#include <math.h>

#define B_    64
#define QLEN  32
#define DLEN  2048
#define WORD  300
#define ENT   128
#define AD    256
#define NK    11
#define VOCAB 50000

typedef __bf16 bf16x8 __attribute__((ext_vector_type(8)));
typedef __bf16 bf16x4 __attribute__((ext_vector_type(4)));
typedef __bf16 bf16x2 __attribute__((ext_vector_type(2)));
typedef float  f32x4  __attribute__((ext_vector_type(4)));

// ---------------------------------------------------------------------------
// W-pack: Wtp (K=320 pad, 160 tiles) + Wep (K=128, 64 tiles), MFMA-B order.
// Also zeroes ksum+simsum (24576 floats) — replaces the memset dispatch.
// ---------------------------------------------------------------------------
__global__ __launch_bounds__(256) void knrm_wpack(
    const float* __restrict__ Wt, const float* __restrict__ We,
    const float* __restrict__ bt, const float* __restrict__ be,
    __bf16* __restrict__ Wtp, __bf16* __restrict__ Wep,
    float* __restrict__ bias, float* __restrict__ zbuf)
{
    const int idx = blockIdx.x * 256 + threadIdx.x;   // 0..14335
    if (idx < AD) bias[idx] = bt[idx] + be[idx];
    if (idx * 2 < 24576) {
        zbuf[idx * 2]     = 0.f;
        zbuf[idx * 2 + 1] = 0.f;
    }
    const int tile = idx >> 6, l = idx & 63;
    bf16x8 h;
    if (tile < 160) {
        const int s = tile >> 4, nb = tile & 15;
        const int col = nb * 16 + (l & 15);
        const int k0  = s * 32 + (l >> 4) * 8;
        #pragma unroll
        for (int j = 0; j < 8; ++j) {
            const int k = k0 + j;
            h[j] = (__bf16)((k < WORD) ? Wt[(size_t)k * AD + col] : 0.f);
        }
        *(bf16x8*)((char*)Wtp + (size_t)idx * 16) = h;
    } else {
        const int t2 = tile - 160;
        const int s = t2 >> 4, nb = t2 & 15;
        const int col = nb * 16 + (l & 15);
        const int k0  = s * 32 + (l >> 4) * 8;
        #pragma unroll
        for (int j = 0; j < 8; ++j)
            h[j] = (__bf16)We[(size_t)(k0 + j) * AD + col];
        *(bf16x8*)((char*)Wep + (size_t)(idx - 10240) * 16) = h;
    }
}

// ---------------------------------------------------------------------------
// P-GEMM (64 rows/block). P[v] = emb[v] @ Wt, bf16, permuted rows (512B):
// offset(col) = (col>>6)*128 + (col&15)*8 + ((col>>4)&3)*2  -> coalesced store
// ---------------------------------------------------------------------------
__global__ __launch_bounds__(256) void knrm_pgemm(
    const float* __restrict__ emb,
    const __bf16* __restrict__ Wtp,
    char* __restrict__ P)
{
    __shared__ __align__(16) char sm[40960];   // A [64][320] bf16 swizzled
    const int tid = threadIdx.x;
    const int v0  = blockIdx.x * 64;

    #pragma unroll
    for (int u = 0; u < 20; ++u) {
        const int idx  = u * 256 + tid;        // 0..5119
        const int r    = idx / 80;
        const int slot = idx - r * 80;
        const int k    = slot * 4;
        f32x4 v = (f32x4){0.f, 0.f, 0.f, 0.f};
        if (k < WORD && v0 + r < VOCAB)
            v = *(const f32x4*)(emb + (size_t)(v0 + r) * WORD + k);
        bf16x4 hv;
        #pragma unroll
        for (int c = 0; c < 4; ++c) hv[c] = (__bf16)v[c];
        *(bf16x4*)(sm + ((r * 640 + slot * 8) ^ ((r & 7) << 4))) = hv;
    }
    __syncthreads();

    const int w  = tid >> 6;
    const int l  = tid & 63;
    const int lr = l & 15;
    const int lg = l >> 4;

    f32x4 acc[4][4];
    #pragma unroll
    for (int mf = 0; mf < 4; ++mf)
        #pragma unroll
        for (int nf = 0; nf < 4; ++nf)
            acc[mf][nf] = (f32x4){0.f, 0.f, 0.f, 0.f};

    #pragma unroll
    for (int t = 0; t < 10; ++t) {
        bf16x8 a[4];
        #pragma unroll
        for (int mf = 0; mf < 4; ++mf) {
            const int row = mf * 16 + lr;
            a[mf] = *(const bf16x8*)(sm +
                ((row * 640 + t * 64 + lg * 16) ^ ((row & 7) << 4)));
        }
        bf16x8 wv[4];
        #pragma unroll
        for (int nf = 0; nf < 4; ++nf) {
            const int tile = t * 16 + w * 4 + nf;
            wv[nf] = *(const bf16x8*)((const char*)Wtp + (size_t)tile * 1024 + l * 16);
        }
        #pragma unroll
        for (int mf = 0; mf < 4; ++mf)
            #pragma unroll
            for (int nf = 0; nf < 4; ++nf)
                acc[mf][nf] = __builtin_amdgcn_mfma_f32_16x16x32_bf16(
                    a[mf], wv[nf], acc[mf][nf], 0, 0, 0);
    }

    #pragma unroll
    for (int mf = 0; mf < 4; ++mf)
        #pragma unroll
        for (int reg = 0; reg < 4; ++reg) {
            const int v = v0 + mf * 16 + lg * 4 + reg;
            if (v < VOCAB) {
                bf16x4 h;
                #pragma unroll
                for (int nf = 0; nf < 4; ++nf) h[nf] = (__bf16)acc[mf][nf][reg];
                *(bf16x4*)(P + (size_t)v * 512 + w * 128 + lr * 8) = h;
            }
        }
}

// ---------------------------------------------------------------------------
// Query transform: 32 rows (1 batch)/block, grid 64. relu(P[tok]+qent@We+b),
// normalize, zero padded rows; write qhatF in B-FRAGMENT TILE order.
// ---------------------------------------------------------------------------
__global__ __launch_bounds__(256) void knrm_qtrans(
    const int* __restrict__ tok,
    const float* __restrict__ ent,
    const char* __restrict__ Pp,
    const __bf16* __restrict__ Wep,
    const float* __restrict__ bias,
    char* __restrict__ qhatF)
{
    __shared__ __align__(16) char sm[16384 + 256];   // T [32][256] bf16 swz
    float* ssq  = (float*)(sm + 16384);              // [32]
    int*   toks = (int*)(sm + 16384 + 128);          // [32]

    const int tid  = threadIdx.x;
    const int row0 = blockIdx.x * 32;
    if (tid < 32) { toks[tid] = tok[row0 + tid] + 1; ssq[tid] = 0.f; }
    __syncthreads();

    const int wN = tid >> 6;
    const int l  = tid & 63;
    const int lr = l & 15;
    const int lg = l >> 4;
    const float* __restrict__ ebase = ent + (size_t)row0 * ENT;

    f32x4 acc[2][4];
    #pragma unroll
    for (int mf = 0; mf < 2; ++mf)
        #pragma unroll
        for (int nf = 0; nf < 4; ++nf)
            acc[mf][nf] = (f32x4){0.f, 0.f, 0.f, 0.f};

    bf16x4 pv[2][4];
    #pragma unroll
    for (int mf = 0; mf < 2; ++mf)
        #pragma unroll
        for (int reg = 0; reg < 4; ++reg) {
            const int r = mf * 16 + lg * 4 + reg;
            pv[mf][reg] = *(const bf16x4*)(Pp +
                (size_t)toks[r] * 512 + wN * 128 + lr * 8);
        }

    #pragma unroll
    for (int t = 0; t < 4; ++t) {
        bf16x8 a[2];
        #pragma unroll
        for (int mf = 0; mf < 2; ++mf) {
            const float* rp = ebase + (size_t)(mf * 16 + lr) * ENT + t * 32 + lg * 8;
            const f32x4 u0 = *(const f32x4*)rp;
            const f32x4 u1 = *(const f32x4*)(rp + 4);
            #pragma unroll
            for (int c = 0; c < 4; ++c) {
                a[mf][c]     = (__bf16)u0[c];
                a[mf][c + 4] = (__bf16)u1[c];
            }
        }
        bf16x8 wv[4];
        #pragma unroll
        for (int nf = 0; nf < 4; ++nf) {
            const int tile = t * 16 + wN * 4 + nf;
            wv[nf] = *(const bf16x8*)((const char*)Wep + (size_t)tile * 1024 + l * 16);
        }
        #pragma unroll
        for (int mf = 0; mf < 2; ++mf)
            #pragma unroll
            for (int nf = 0; nf < 4; ++nf)
                acc[mf][nf] = __builtin_amdgcn_mfma_f32_16x16x32_bf16(
                    a[mf], wv[nf], acc[mf][nf], 0, 0, 0);
    }

    float bv[4];
    #pragma unroll
    for (int nf = 0; nf < 4; ++nf) bv[nf] = bias[wN * 64 + nf * 16 + lr];
    float sq[2][4];
    #pragma unroll
    for (int mf = 0; mf < 2; ++mf)
        #pragma unroll
        for (int reg = 0; reg < 4; ++reg) {
            float s = 0.f;
            #pragma unroll
            for (int nf = 0; nf < 4; ++nf) {
                const float v = fmaxf(acc[mf][nf][reg] + (float)pv[mf][reg][nf]
                                      + bv[nf], 0.f);
                acc[mf][nf][reg] = v;
                s = fmaf(v, v, s);
            }
            sq[mf][reg] = s;
        }
    #pragma unroll
    for (int m = 1; m <= 8; m <<= 1)
        #pragma unroll
        for (int mf = 0; mf < 2; ++mf)
            #pragma unroll
            for (int reg = 0; reg < 4; ++reg)
                sq[mf][reg] += __shfl_xor(sq[mf][reg], m, 64);
    if (lr == 0) {
        #pragma unroll
        for (int mf = 0; mf < 2; ++mf)
            #pragma unroll
            for (int reg = 0; reg < 4; ++reg)
                atomicAdd(&ssq[mf * 16 + lg * 4 + reg], sq[mf][reg]);
    }
    #pragma unroll
    for (int mf = 0; mf < 2; ++mf)
        #pragma unroll
        for (int nf = 0; nf < 4; ++nf)
            #pragma unroll
            for (int reg = 0; reg < 4; ++reg) {
                const int r    = mf * 16 + lg * 4 + reg;
                const int col  = wN * 64 + nf * 16 + lr;
                const int byte = (r * 512 + col * 2) ^ ((r & 7) << 4);
                *(__bf16*)(sm + byte) = (__bf16)acc[mf][nf][reg];
            }
    __syncthreads();

    // readout in fragment-tile order: 16 tiles x 64 lanes x 16B
    char* qb = qhatF + (size_t)blockIdx.x * 16384;
    #pragma unroll
    for (int it = 0; it < 4; ++it) {
        const int idx = it * 256 + tid;         // 0..1023
        const int tile = idx >> 6, l2 = idx & 63;
        const int s  = tile >> 1, qt = tile & 1;
        const int row = qt * 16 + (l2 & 15);
        const int k0  = s * 32 + (l2 >> 4) * 8;
        const int byte = (row * 512 + k0 * 2) ^ ((row & 7) << 4);
        bf16x8 hv = *(const bf16x8*)(sm + byte);
        const float rn = (toks[row] == 0) ? 0.f
                                          : 1.f / (sqrtf(ssq[row]) + 1e-9f);
        #pragma unroll
        for (int j = 0; j < 8; ++j) hv[j] = (__bf16)((float)hv[j] * rn);
        *(bf16x8*)(qb + tile * 1024 + l2 * 16) = hv;
    }
}

// ---------------------------------------------------------------------------
// Fused v14 (best measured): 32 docs/block, 4 waves, __launch_bounds__(256,4);
// tail stores normalized sims bf16.
// ---------------------------------------------------------------------------
__global__ __launch_bounds__(256, 4) void knrm_fused5(
    const int* __restrict__ dtok,
    const float* __restrict__ dent,
    const char* __restrict__ Pp,
    const __bf16* __restrict__ Wep,
    const float* __restrict__ bias,
    const char* __restrict__ qhatF,
    __bf16* __restrict__ simsO)   // [B, DLEN, QLEN] bf16
{
    __shared__ __align__(16) char sm[16384 + 256];
    float* ssq  = (float*)(sm + 16384);          // [32]
    int*   toks = (int*)(sm + 16384 + 128);      // [32]

    const int tid = threadIdx.x;
    const int b   = blockIdx.y;
    const int d0  = blockIdx.x * 32;
    const int drow0 = b * DLEN + d0;
    const int w  = tid >> 6;
    const int l  = tid & 63;
    const int lr = l & 15;
    const int lg = l >> 4;

    if (tid < 32) { toks[tid] = dtok[drow0 + tid] + 1; ssq[tid] = 0.f; }

    // stage dent -> Ab bf16 [32][128] swz
    #pragma unroll
    for (int u = 0; u < 4; ++u) {
        const int slot = u * 256 + tid;
        const int r    = slot >> 5;
        const int c4   = (slot & 31) * 4;
        const f32x4 v = *(const f32x4*)(dent + (size_t)(drow0 + r) * ENT + c4);
        bf16x4 hv;
        #pragma unroll
        for (int c = 0; c < 4; ++c) hv[c] = (__bf16)v[c];
        *(bf16x4*)(sm + ((r * 256 + c4 * 2) ^ ((r & 7) << 4))) = hv;
    }
    __syncthreads();

    // early P gather
    bf16x4 pv[2][4];
    #pragma unroll
    for (int mf = 0; mf < 2; ++mf)
        #pragma unroll
        for (int reg = 0; reg < 4; ++reg) {
            const int doc = mf * 16 + lg * 4 + reg;
            pv[mf][reg] = *(const bf16x4*)(Pp +
                (size_t)toks[doc] * 512 + w * 128 + lr * 8);
        }

    f32x4 acc[2][4];
    #pragma unroll
    for (int mf = 0; mf < 2; ++mf)
        #pragma unroll
        for (int nf = 0; nf < 4; ++nf)
            acc[mf][nf] = (f32x4){0.f, 0.f, 0.f, 0.f};

    #pragma unroll
    for (int t = 0; t < 4; ++t) {
        bf16x8 a[2];
        #pragma unroll
        for (int mf = 0; mf < 2; ++mf) {
            const int row = mf * 16 + lr;
            a[mf] = *(const bf16x8*)(sm +
                ((row * 256 + t * 64 + lg * 16) ^ ((row & 7) << 4)));
        }
        bf16x8 wv[4];
        #pragma unroll
        for (int nf = 0; nf < 4; ++nf) {
            const int tile = t * 16 + w * 4 + nf;
            wv[nf] = *(const bf16x8*)((const char*)Wep + (size_t)tile * 1024 + l * 16);
        }
        #pragma unroll
        for (int mf = 0; mf < 2; ++mf)
            #pragma unroll
            for (int nf = 0; nf < 4; ++nf)
                acc[mf][nf] = __builtin_amdgcn_mfma_f32_16x16x32_bf16(
                    a[mf], wv[nf], acc[mf][nf], 0, 0, 0);
    }
    __syncthreads();   // Ab reads done; region reusable as T

    float bv[4];
    #pragma unroll
    for (int nf = 0; nf < 4; ++nf) bv[nf] = bias[w * 64 + nf * 16 + lr];
    float sq[2][4];
    #pragma unroll
    for (int mf = 0; mf < 2; ++mf)
        #pragma unroll
        for (int reg = 0; reg < 4; ++reg) {
            float s = 0.f;
            #pragma unroll
            for (int nf = 0; nf < 4; ++nf) {
                const float v = fmaxf(acc[mf][nf][reg] + (float)pv[mf][reg][nf]
                                      + bv[nf], 0.f);
                acc[mf][nf][reg] = v;
                s = fmaf(v, v, s);
            }
            sq[mf][reg] = s;
        }
    #pragma unroll
    for (int m = 1; m <= 8; m <<= 1)
        #pragma unroll
        for (int mf = 0; mf < 2; ++mf)
            #pragma unroll
            for (int reg = 0; reg < 4; ++reg)
                sq[mf][reg] += __shfl_xor(sq[mf][reg], m, 64);
    if (lr == 0) {
        #pragma unroll
        for (int mf = 0; mf < 2; ++mf)
            #pragma unroll
            for (int reg = 0; reg < 4; ++reg)
                atomicAdd(&ssq[mf * 16 + lg * 4 + reg], sq[mf][reg]);
    }
    // T write [doc][256] bf16: byte = doc*512 + (col*2 ^ ((doc&15)<<4))
    #pragma unroll
    for (int mf = 0; mf < 2; ++mf)
        #pragma unroll
        for (int nf = 0; nf < 4; ++nf)
            #pragma unroll
            for (int reg = 0; reg < 4; ++reg) {
                const int doc  = mf * 16 + lg * 4 + reg;
                const int col  = w * 64 + nf * 16 + lr;
                const int byte = doc * 512 + ((col * 2) ^ ((doc & 15) << 4));
                *(__bf16*)(sm + byte) = (__bf16)acc[mf][nf][reg];
            }
    __syncthreads();   // T + ssq visible

    // sims: wave -> dtile=w&1 (16 docs, M), qtile=w>>1 (16 q, N)
    const int dtile = w & 1, qtile = w >> 1;
    const int tdoc  = dtile * 16 + lr;
    const char* __restrict__ qb = qhatF + (size_t)b * 16384;
    f32x4 s0 = (f32x4){0.f, 0.f, 0.f, 0.f};
    #pragma unroll
    for (int s = 0; s < 8; ++s) {
        const bf16x8 ta = *(const bf16x8*)(sm +
            (tdoc * 512 + ((s * 64 + lg * 16) ^ ((tdoc & 15) << 4))));
        const bf16x8 qv = *(const bf16x8*)(qb + (s * 2 + qtile) * 1024 + l * 16);
        s0 = __builtin_amdgcn_mfma_f32_16x16x32_bf16(ta, qv, s0, 0, 0, 0);
    }

    // store normalized sims (bf16)
    __bf16* so = simsO + ((size_t)b * DLEN + d0) * QLEN;
    #pragma unroll
    for (int reg = 0; reg < 4; ++reg) {
        const int doc = dtile * 16 + lg * 4 + reg;
        const float dnv = (toks[doc] == 0) ? 0.f
                                           : 1.f / (sqrtf(ssq[doc]) + 1e-9f);
        so[(size_t)doc * QLEN + qtile * 16 + lr] = (__bf16)(s0[reg] * dnv);
    }
}

// ---------------------------------------------------------------------------
// Streaming RBF pass: grid (16, 64), 256 thr. Each block: 128 docs x 32 q.
// Paired bf16x2 loads (2 q-columns per thread); sigma=0.001 kernel guarded.
// ---------------------------------------------------------------------------
__global__ __launch_bounds__(256) void knrm_rbf(
    const __bf16* __restrict__ simsI,
    float* __restrict__ ksum,
    float* __restrict__ simsum)
{
    __shared__ float red[384];
    const int tid = threadIdx.x;
    const int b   = blockIdx.y;
    const int d0  = blockIdx.x * 128;
    const int q0  = (tid & 15) * 2;
    for (int i = tid; i < 384; i += 256) red[i] = 0.f;
    __syncthreads();

    const __bf16* __restrict__ base = simsI + ((size_t)b * DLEN + d0) * QLEN;
    float kq[2][12];
    #pragma unroll
    for (int p = 0; p < 2; ++p)
        #pragma unroll
        for (int k = 0; k < 12; ++k) kq[p][k] = 0.f;

    #pragma unroll
    for (int u = 0; u < 8; ++u) {
        const bf16x2 pr = *(const bf16x2*)(base + u * 512 + tid * 2);
        #pragma unroll
        for (int p = 0; p < 2; ++p) {
            const float sv = (float)pr[p];
            kq[p][11] += sv;
            const float v5 = __expf(fmaf(10.f, sv, -50.f * sv * sv));
            const float gU = __expf(20.f * sv);
            const float gD = __expf(-20.f * sv);
            float t = v5;
            kq[p][5] += t * 0.60653066f;
            t *= gD; kq[p][4] += t * 0.60653066f;
            t *= gD; kq[p][3] += t * 0.011108997f;
            t *= gD; kq[p][2] += t * 3.7266532e-06f;
            t *= gD; kq[p][1] += t * 2.2895532e-11f;
            t *= gD; kq[p][0] += t * 2.5767571e-18f;
            t = v5;
            t *= gU; kq[p][6] += t * 0.011108997f;
            t *= gU; kq[p][7] += t * 3.7266532e-06f;
            t *= gU; kq[p][8] += t * 2.2895532e-11f;
            t *= gU; kq[p][9] += t * 2.5767571e-18f;
            if (sv > 0.98f) {
                const float t10 = sv - 1.0f;
                kq[p][10] += __expf(-500000.f * t10 * t10);
            }
        }
    }

    // lanes l, l^16, l^32, l^48 share the q-pair: butterfly then LDS reduce
    #pragma unroll
    for (int m = 16; m <= 32; m <<= 1)
        #pragma unroll
        for (int p = 0; p < 2; ++p)
            #pragma unroll
            for (int k = 0; k < 12; ++k)
                kq[p][k] += __shfl_xor(kq[p][k], m, 64);
    if ((tid & 63) < 16) {
        #pragma unroll
        for (int p = 0; p < 2; ++p)
            #pragma unroll
            for (int k = 0; k < 12; ++k)
                atomicAdd(&red[k * 32 + q0 + p], kq[p][k]);
    }
    __syncthreads();

    for (int i = tid; i < 384; i += 256) {
        const int k = i >> 5, qq = i & 31;
        if (k < NK) atomicAdd(&ksum[((size_t)b * NK + k) * QLEN + qq], red[i]);
        else        atomicAdd(&simsum[b * QLEN + qq], red[i]);
    }
}

// ---------------------------------------------------------------------------
__global__ __launch_bounds__(384) void knrm_final(
    const float* __restrict__ ksum,
    const float* __restrict__ simsum,
    const float* __restrict__ Wc, const float* __restrict__ bc,
    float* __restrict__ out)
{
    __shared__ float redq[NK][QLEN];
    __shared__ float res[NK];
    const int b = blockIdx.x;
    const int t = threadIdx.x;
    if (t < NK * QLEN) {
        const int k = t >> 5;
        const int q = t & 31;
        const float ms = simsum[b * QLEN + q];
        redq[k][q] = (ms != 0.0f)
            ? logf(ksum[((size_t)b * NK + k) * QLEN + q] + 1e-6f)
            : 0.0f;
    }
    __syncthreads();
    if (t < NK) {
        float s = 0.f;
        for (int q = 0; q < QLEN; ++q) s += redq[t][q];
        res[t] = s;
    }
    __syncthreads();
    if (t == 0) {
        float s = bc[0];
        for (int k = 0; k < NK; ++k) s += res[k] * Wc[k];
        out[b] = s;
    }
}

// ---------------------------------------------------------------------------
extern "C" void kernel_launch(void* const* d_in, const int* in_sizes, int n_in,
                              void* d_out, int out_size, void* d_ws, size_t ws_size,
                              hipStream_t stream)
{
    (void)in_sizes; (void)n_in; (void)out_size; (void)ws_size;
    const int*   qtok = (const int*)d_in[0];
    const int*   dtok = (const int*)d_in[1];
    const float* qent = (const float*)d_in[2];
    const float* dent = (const float*)d_in[3];
    const float* emb  = (const float*)d_in[4];
    const float* Wt   = (const float*)d_in[5];
    const float* bt   = (const float*)d_in[6];
    const float* We   = (const float*)d_in[7];
    const float* be   = (const float*)d_in[8];
    const float* Wc   = (const float*)d_in[9];
    const float* bc   = (const float*)d_in[10];
    float* out = (float*)d_out;

    char* ws = (char*)d_ws;
    const size_t off_qhat = 0;                               // 1,048,576
    const size_t off_Wtp  = off_qhat + 1048576;              //   163,840
    const size_t off_Wep  = off_Wtp  + 163840;               //    65,536
    const size_t off_bias = off_Wep  + 65536;                //     1,024
    const size_t off_ksum = off_bias + 1024;                 //    90,112
    const size_t off_sim  = off_ksum + 90112;                //     8,192
    const size_t off_P    = off_sim  + 8192;                 // 25,600,000
    const size_t off_sims = off_P    + 25600000;             //  8,388,608

    char*   qhatF = ws + off_qhat;
    __bf16* Wtp   = (__bf16*)(ws + off_Wtp);
    __bf16* Wep   = (__bf16*)(ws + off_Wep);
    float*  bias  = (float*)(ws + off_bias);
    float*  ksum  = (float*)(ws + off_ksum);
    float*  simsum= (float*)(ws + off_sim);
    char*   P     = ws + off_P;
    __bf16* simsX = (__bf16*)(ws + off_sims);

    knrm_wpack<<<dim3(56), dim3(256), 0, stream>>>(
        Wt, We, bt, be, Wtp, Wep, bias, ksum);
    knrm_pgemm<<<dim3((VOCAB + 63) / 64), dim3(256), 0, stream>>>(emb, Wtp, P);
    knrm_qtrans<<<dim3(64), dim3(256), 0, stream>>>(
        qtok, qent, P, Wep, bias, qhatF);
    knrm_fused5<<<dim3(DLEN / 32, B_), dim3(256), 0, stream>>>(
        dtok, dent, P, Wep, bias, qhatF, simsX);
    knrm_rbf<<<dim3(16, B_), dim3(256), 0, stream>>>(simsX, ksum, simsum);
    knrm_final<<<dim3(B_), dim3(384), 0, stream>>>(ksum, simsum, Wc, bc, out);
}